// Round 2
// baseline (221.037 us; speedup 1.0000x reference)
//
#include <hip/hip_runtime.h>
#include <hip/hip_bf16.h>
#include <math.h>

typedef __bf16 bf16t;
typedef __bf16 bf8v __attribute__((ext_vector_type(8)));
typedef float  f4v  __attribute__((ext_vector_type(4)));

#define DD  4
#define FF  64
#define HH  128
#define FIN 129
#define MT  128   // rows per block

// XOR-swizzled LDS index: element [row][k] of a row-major [*][128] bf16 tile,
// 16B chunk (k>>3) XORed with (row&7) -> conflict-free ds_read_b128 at pitch 128.
__device__ __forceinline__ int swz(int row, int k) {
  return row * HH + ((((k >> 3) ^ (row & 7)) << 3) | (k & 7));
}

// ---- weight prep: f32 -> bf16, transposed to [n][k] for B-fragment loads ----
__global__ void prep_weights(const float* __restrict__ w1,
                             const float* __restrict__ w2,
                             const float* __restrict__ w3,
                             bf16t* __restrict__ w1t,
                             bf16t* __restrict__ w2t,
                             bf16t* __restrict__ w3t,
                             float* __restrict__ w1last) {
  int i = blockIdx.x * blockDim.x + threadIdx.x;
  if (i < DD * HH * HH) {            // 65536: w1t + w2t
    int d = i >> 14, n = (i >> 7) & 127, k = i & 127;
    w1t[i] = (bf16t)w1[(d * FIN + k) * HH + n];
    w2t[i] = (bf16t)w2[(d * HH + k) * HH + n];
  }
  if (i < HH * HH) {                 // 16384: w3t
    int n = i >> 7, k = i & 127;
    w3t[i] = (bf16t)w3[k * HH + n];
  }
  if (i < DD * HH) {                 // 512: last feat column of w1, kept f32
    int d = i >> 7, n = i & 127;
    w1last[i] = w1[(d * FIN + 128) * HH + n];
  }
}

// Stage a 128x128 bf16 [n][k] weight tile (2048 16B chunks) into swizzled LDS.
// chunk idx -> row = idx/16, k-chunk = idx%16. Coalesced 16B loads.
__device__ __forceinline__ void stage_w(const bf16t* __restrict__ w,
                                        bf16t* __restrict__ ldsW, int tid) {
  const bf8v* src = (const bf8v*)w;
  #pragma unroll
  for (int c2 = 0; c2 < 8; ++c2) {
    int idx = tid + c2 * 256;          // 0..2047
    int n = idx >> 4, seg = idx & 15;
    *(bf8v*)&ldsW[swz(n, seg * 8)] = src[idx];
  }
}

__launch_bounds__(256, 2)
__global__ void fourier_mlp(
    const float* __restrict__ cont,   // [N,4]
    const float* __restrict__ freqs,  // [4,64]
    const float* __restrict__ b1,     // [4,128]
    const float* __restrict__ ln1g,
    const float* __restrict__ ln1b,
    const float* __restrict__ b2,
    const float* __restrict__ outg,   // [128]
    const float* __restrict__ outb,
    const float* __restrict__ b3,
    const bf16t* __restrict__ w1t,    // [4][128][128] bf16, [d][n][k]
    const bf16t* __restrict__ w2t,    // [4][128][128]
    const bf16t* __restrict__ w3t,    // [128][128]
    const float* __restrict__ w1last, // [4][128]
    float* __restrict__ out)          // [N,128] f32
{
  __shared__ __align__(16) bf16t ldsA[MT * HH];  // 32 KB: feat / h / emb tiles
  __shared__ __align__(16) bf16t ldsW[HH * HH];  // 32 KB: current weight

  const int tid   = threadIdx.x;
  const int lane  = tid & 63;
  const int wave  = tid >> 6;
  const int q     = lane >> 4;
  const int l15   = lane & 15;
  const int rowbase = blockIdx.x * MT;
  const int wrow  = wave * 32;     // wave's 32-row slab in the block tile
  const int frow  = tid >> 1;      // feat staging: row 0..127
  const int fhalf = tid & 1;       // 0: cos half, 1: sin half

  const f4v fzero = {0.0f, 0.0f, 0.0f, 0.0f};

  f4v emb[2][8];
  #pragma unroll
  for (int rt = 0; rt < 2; ++rt)
    #pragma unroll
    for (int nt = 0; nt < 8; ++nt) emb[rt][nt] = fzero;

  for (int d = 0; d < DD; ++d) {
    __syncthreads();  // prior iter's GEMM2 reads of ldsA/ldsW complete

    // ---- stage feat (cos|sin, bf16) into ldsA ----
    {
      float c = cont[(rowbase + frow) * DD + d];
      const float* fr = freqs + d * FF;
      #pragma unroll
      for (int jc = 0; jc < 8; ++jc) {
        bf8v pk;
        #pragma unroll
        for (int u = 0; u < 8; ++u) {
          float t = c * fr[jc * 8 + u];   // revolutions: sin(2*pi*t)
          t = t - floorf(t);
          float v = fhalf ? __builtin_amdgcn_sinf(t)
                          : __builtin_amdgcn_cosf(t);
          pk[u] = (bf16t)v;
        }
        *(bf8v*)&ldsA[swz(frow, fhalf * 64 + jc * 8)] = pk;
      }
    }
    stage_w(w1t + d * HH * HH, ldsW, tid);
    __syncthreads();

    // ---- GEMM1: h = feat @ w1[:128,:] ----
    f4v acc[2][8];
    #pragma unroll
    for (int rt = 0; rt < 2; ++rt)
      #pragma unroll
      for (int nt = 0; nt < 8; ++nt) acc[rt][nt] = fzero;

    #pragma unroll
    for (int kk = 0; kk < 128; kk += 32) {
      bf8v a0 = *(const bf8v*)&ldsA[swz(wrow + l15,      kk + q * 8)];
      bf8v a1 = *(const bf8v*)&ldsA[swz(wrow + 16 + l15, kk + q * 8)];
      #pragma unroll
      for (int nt = 0; nt < 8; ++nt) {
        bf8v b = *(const bf8v*)&ldsW[swz(nt * 16 + l15, kk + q * 8)];
        acc[0][nt] = __builtin_amdgcn_mfma_f32_16x16x32_bf16(a0, b, acc[0][nt], 0, 0, 0);
        acc[1][nt] = __builtin_amdgcn_mfma_f32_16x16x32_bf16(a1, b, acc[1][nt], 0, 0, 0);
      }
    }

    // ---- epilogue: + b1 + rank-1 (f32 exact), LayerNorm, ReLU -> ldsA (bf16) ----
    float w1l[8], b1v[8], gv[8], bv[8];
    #pragma unroll
    for (int nt = 0; nt < 8; ++nt) {
      int n = nt * 16 + l15;
      w1l[nt] = w1last[d * HH + n];
      b1v[nt] = b1[d * HH + n];
      gv[nt]  = ln1g[d * HH + n];
      bv[nt]  = ln1b[d * HH + n];
    }
    #pragma unroll
    for (int rt = 0; rt < 2; ++rt) {
      float cv[4], s[4], ss[4];
      #pragma unroll
      for (int r = 0; r < 4; ++r) {
        cv[r] = cont[(rowbase + wrow + rt * 16 + q * 4 + r) * DD + d];
        s[r] = 0.0f; ss[r] = 0.0f;
      }
      #pragma unroll
      for (int nt = 0; nt < 8; ++nt)
        #pragma unroll
        for (int r = 0; r < 4; ++r) {
          float v = acc[rt][nt][r] + b1v[nt] + cv[r] * w1l[nt];
          acc[rt][nt][r] = v;
          s[r] += v; ss[r] += v * v;
        }
      #pragma unroll
      for (int m = 1; m < 16; m <<= 1)
        #pragma unroll
        for (int r = 0; r < 4; ++r) {
          s[r]  += __shfl_xor(s[r],  m);
          ss[r] += __shfl_xor(ss[r], m);
        }
      #pragma unroll
      for (int r = 0; r < 4; ++r) {
        float mu   = s[r] * (1.0f / 128.0f);
        float var  = ss[r] * (1.0f / 128.0f) - mu * mu;
        float rstd = rsqrtf(var + 1e-5f);
        int mrow = wrow + rt * 16 + q * 4 + r;
        #pragma unroll
        for (int nt = 0; nt < 8; ++nt) {
          float v = (acc[rt][nt][r] - mu) * rstd * gv[nt] + bv[nt];
          v = fmaxf(v, 0.0f);
          // own slab: no cross-wave hazard, barrier-free write
          ldsA[swz(mrow, nt * 16 + l15)] = (bf16t)v;
        }
      }
    }
    __syncthreads();  // all waves done with w1t reads
    stage_w(w2t + d * HH * HH, ldsW, tid);
    __syncthreads();

    // ---- GEMM2: emb += h_relu @ w2 ----
    #pragma unroll
    for (int kk = 0; kk < 128; kk += 32) {
      bf8v a0 = *(const bf8v*)&ldsA[swz(wrow + l15,      kk + q * 8)];
      bf8v a1 = *(const bf8v*)&ldsA[swz(wrow + 16 + l15, kk + q * 8)];
      #pragma unroll
      for (int nt = 0; nt < 8; ++nt) {
        bf8v b = *(const bf8v*)&ldsW[swz(nt * 16 + l15, kk + q * 8)];
        emb[0][nt] = __builtin_amdgcn_mfma_f32_16x16x32_bf16(a0, b, emb[0][nt], 0, 0, 0);
        emb[1][nt] = __builtin_amdgcn_mfma_f32_16x16x32_bf16(a1, b, emb[1][nt], 0, 0, 0);
      }
    }
    // + b2[d]
    #pragma unroll
    for (int nt = 0; nt < 8; ++nt) {
      float b2v = b2[d * HH + nt * 16 + l15];
      #pragma unroll
      for (int rt = 0; rt < 2; ++rt)
        #pragma unroll
        for (int r = 0; r < 4; ++r) emb[rt][nt][r] += b2v;
    }
  } // d loop

  // ---- final LayerNorm + ReLU on emb -> ldsA (bf16) ----
  {
    float gv[8], bv[8];
    #pragma unroll
    for (int nt = 0; nt < 8; ++nt) {
      gv[nt] = outg[nt * 16 + l15];
      bv[nt] = outb[nt * 16 + l15];
    }
    #pragma unroll
    for (int rt = 0; rt < 2; ++rt) {
      float s[4], ss[4];
      #pragma unroll
      for (int r = 0; r < 4; ++r) { s[r] = 0.0f; ss[r] = 0.0f; }
      #pragma unroll
      for (int nt = 0; nt < 8; ++nt)
        #pragma unroll
        for (int r = 0; r < 4; ++r) {
          float v = emb[rt][nt][r];
          s[r] += v; ss[r] += v * v;
        }
      #pragma unroll
      for (int m = 1; m < 16; m <<= 1)
        #pragma unroll
        for (int r = 0; r < 4; ++r) {
          s[r]  += __shfl_xor(s[r],  m);
          ss[r] += __shfl_xor(ss[r], m);
        }
      #pragma unroll
      for (int r = 0; r < 4; ++r) {
        float mu   = s[r] * (1.0f / 128.0f);
        float var  = ss[r] * (1.0f / 128.0f) - mu * mu;
        float rstd = rsqrtf(var + 1e-5f);
        int mrow = wrow + rt * 16 + q * 4 + r;
        #pragma unroll
        for (int nt = 0; nt < 8; ++nt) {
          float v = (emb[rt][nt][r] - mu) * rstd * gv[nt] + bv[nt];
          v = fmaxf(v, 0.0f);
          ldsA[swz(mrow, nt * 16 + l15)] = (bf16t)v;
        }
      }
    }
  }
  __syncthreads();  // all waves done with w2t reads
  stage_w(w3t, ldsW, tid);
  __syncthreads();

  // ---- GEMM3: out = ln_relu(emb) @ w3 + b3 ----
  f4v acc[2][8];
  {
    const f4v z = {0.0f, 0.0f, 0.0f, 0.0f};
    #pragma unroll
    for (int rt = 0; rt < 2; ++rt)
      #pragma unroll
      for (int nt = 0; nt < 8; ++nt) acc[rt][nt] = z;
  }
  #pragma unroll
  for (int kk = 0; kk < 128; kk += 32) {
    bf8v a0 = *(const bf8v*)&ldsA[swz(wrow + l15,      kk + q * 8)];
    bf8v a1 = *(const bf8v*)&ldsA[swz(wrow + 16 + l15, kk + q * 8)];
    #pragma unroll
    for (int nt = 0; nt < 8; ++nt) {
      bf8v b = *(const bf8v*)&ldsW[swz(nt * 16 + l15, kk + q * 8)];
      acc[0][nt] = __builtin_amdgcn_mfma_f32_16x16x32_bf16(a0, b, acc[0][nt], 0, 0, 0);
      acc[1][nt] = __builtin_amdgcn_mfma_f32_16x16x32_bf16(a1, b, acc[1][nt], 0, 0, 0);
    }
  }
  #pragma unroll
  for (int nt = 0; nt < 8; ++nt) {
    float b3v = b3[nt * 16 + l15];
    #pragma unroll
    for (int rt = 0; rt < 2; ++rt)
      #pragma unroll
      for (int r = 0; r < 4; ++r)
        out[(rowbase + wrow + rt * 16 + q * 4 + r) * HH + nt * 16 + l15] =
            acc[rt][nt][r] + b3v;
  }
}

extern "C" void kernel_launch(void* const* d_in, const int* in_sizes, int n_in,
                              void* d_out, int out_size, void* d_ws, size_t ws_size,
                              hipStream_t stream) {
  const float* cont  = (const float*)d_in[0];
  const float* freqs = (const float*)d_in[1];
  const float* w1    = (const float*)d_in[2];
  const float* b1    = (const float*)d_in[3];
  const float* ln1g  = (const float*)d_in[4];
  const float* ln1b  = (const float*)d_in[5];
  const float* w2    = (const float*)d_in[6];
  const float* b2    = (const float*)d_in[7];
  const float* outg  = (const float*)d_in[8];
  const float* outb  = (const float*)d_in[9];
  const float* w3    = (const float*)d_in[10];
  const float* b3    = (const float*)d_in[11];
  float* out = (float*)d_out;

  // ws layout: w1t[65536] bf16 | w2t[65536] bf16 | w3t[16384] bf16 | w1last[512] f32
  bf16t* w1t = (bf16t*)d_ws;
  bf16t* w2t = w1t + DD * HH * HH;
  bf16t* w3t = w2t + DD * HH * HH;
  float* w1last = (float*)((char*)d_ws + (2 * DD * HH * HH + HH * HH) * sizeof(bf16t));

  prep_weights<<<(DD * HH * HH + 255) / 256, 256, 0, stream>>>(
      w1, w2, w3, w1t, w2t, w3t, w1last);

  int n_rows = in_sizes[0] / DD;       // 131072
  int grid = n_rows / MT;              // 1024
  fourier_mlp<<<grid, 256, 0, stream>>>(
      cont, freqs, b1, ln1g, ln1b, b2, outg, outb, b3,
      w1t, w2t, w3t, w1last, out);
}